// Round 11
// baseline (219.924 us; speedup 1.0000x reference)
//
#include <hip/hip_runtime.h>

// GCN on MI355X — round 11: cut redundant L2/B traffic and LDS contention.
//  1) k_mlp: 4 waves/block re-read the same 16KB weight slice per c-chunk
//     (~400 MB L2 traffic total). Now block-cooperatively staged in LDS
//     (sB1 8KB + sB2 8KB, 2 barriers/chunk) -> B-traffic /4.
//  2) k_part: per-wave LDS counter copies (4x391) instead of one shared
//     array -> ~4x less same-address atomic serialization.
//  3) k_agg: 4-edge unroll, two accumulator pairs (breaks fma dep chain).
//  Everything else from round 10.

#define HD 128
#define HD2 256
#define BSHIFT 8             // 256 nodes per bucket -> 391 buckets
#define BNODES 256
#define SRCBITS 17           // N=100000 < 2^17

typedef __attribute__((ext_vector_type(8))) short bf8_t;   // 8 x bf16 (4 VGPR)
typedef __attribute__((ext_vector_type(4))) float f32x4;

static inline size_t align256(size_t x) { return (x + 255) & ~(size_t)255; }

__device__ inline ushort f2bf(float f) {            // RNE f32 -> bf16
    uint u = __float_as_uint(f);
    uint r = u + 0x7fffu + ((u >> 16) & 1u);
    return (ushort)(r >> 16);
}
__device__ inline uint packbf(float a, float b) {
    return (uint)f2bf(a) | ((uint)f2bf(b) << 16);
}

// Phase 1: stream edges once, partition into 391 dst-buckets.
// Per-wave LDS counters (4 copies) cut same-address atomic serialization.
__global__ __launch_bounds__(256) void k_part(const int* __restrict__ ei,
                                              const float* __restrict__ ew,
                                              int* __restrict__ bfill,
                                              uint2* __restrict__ stg,
                                              int E, int nbuck, int cap) {
    __shared__ int lcnt[4][512];
    __shared__ int lbase[4][512];
    int tid = threadIdx.x;
    int wvid = tid >> 6;
    for (int i = tid; i < nbuck; i += 256) {
        lcnt[0][i] = 0; lcnt[1][i] = 0; lcnt[2][i] = 0; lcnt[3][i] = 0;
    }
    __syncthreads();
    bool is64 = (ei[1] == 0) && (ei[3] == 0) && (ei[5] == 0) && (ei[7] == 0);
    int e0 = blockIdx.x * 2048;
    uint pack[8]; uint wb[8]; int bkt[8]; int rank[8];
    for (int u = 0; u < 8; u++) {
        int e = e0 + u * 256 + tid;
        bkt[u] = -1;
        if (e < E) {
            int s, d;
            if (is64) { s = ei[2 * e]; d = ei[2 * (E + e)]; }
            else      { s = ei[e];     d = ei[E + e]; }
            bkt[u] = d >> BSHIFT;
            pack[u] = ((uint)(d & (BNODES - 1)) << SRCBITS) | (uint)s;
            wb[u] = __float_as_uint(ew[e]);
            rank[u] = atomicAdd(&lcnt[wvid][bkt[u]], 1);
        }
    }
    __syncthreads();
    for (int i = tid; i < nbuck; i += 256) {
        int t0 = lcnt[0][i], t1 = lcnt[1][i], t2 = lcnt[2][i], t3 = lcnt[3][i];
        int tot = t0 + t1 + t2 + t3;
        int base = tot ? atomicAdd(&bfill[i], tot) : 0;
        lbase[0][i] = base;
        lbase[1][i] = base + t0;
        lbase[2][i] = base + t0 + t1;
        lbase[3][i] = base + t0 + t1 + t2;
    }
    __syncthreads();
    for (int u = 0; u < 8; u++)
        if (bkt[u] >= 0)
            stg[(size_t)bkt[u] * cap + lbase[wvid][bkt[u]] + rank[u]] =
                make_uint2(pack[u], wb[u]);
}

// Parallel exclusive scan over bucket totals (one block); rowptr[N] = E.
__global__ __launch_bounds__(512) void k_bscan(const int* __restrict__ bfill,
                                               int* __restrict__ cvbase,
                                               int* __restrict__ rowptr,
                                               int nbuck, int N, int E) {
    __shared__ int ws[8];
    int tid = threadIdx.x;
    int lane = tid & 63, wvid = tid >> 6;
    int a = (tid < nbuck) ? bfill[tid] : 0;
    int v = a;
    for (int off = 1; off < 64; off <<= 1) {
        int u = __shfl_up(v, off);
        if (lane >= off) v += u;
    }
    if (lane == 63) ws[wvid] = v;
    __syncthreads();
    int wpre = 0;
    for (int k = 0; k < wvid; k++) wpre += ws[k];
    if (tid < nbuck) cvbase[tid] = v + wpre - a;
    if (tid == 0) rowptr[N] = E;
}

// Phase 2: one 512-thread block per 256-node bucket. LDS count -> scan ->
// ranked scatter into the bucket's private ~32KB cv window (single L2 owner).
// Fused: rowptr emission + deg/dis/p.
__global__ __launch_bounds__(512) void k_fine(const uint2* __restrict__ stg,
                                              const int* __restrict__ bfill,
                                              const int* __restrict__ cvbase,
                                              const float* __restrict__ x,
                                              float* __restrict__ dis,
                                              float* __restrict__ p,
                                              int* __restrict__ rowptr,
                                              int2* __restrict__ cv,
                                              int cap, int N) {
    __shared__ int cnt_l[BNODES];
    __shared__ int base_l[BNODES];
    __shared__ float degf[BNODES];
    __shared__ int wsum[4];
    int b = blockIdx.x, tid = threadIdx.x;
    int n = bfill[b];
    int cb = cvbase[b];
    const uint2* s = stg + (size_t)b * cap;
    if (tid < BNODES) { cnt_l[tid] = 0; degf[tid] = 1.0f; }
    __syncthreads();
    for (int i = tid; i < n; i += 512)
        atomicAdd(&cnt_l[s[i].x >> SRCBITS], 1);
    __syncthreads();
    int lane = tid & 63, wvid = tid >> 6;
    int a = 0;
    if (tid < BNODES) { a = cnt_l[tid]; cnt_l[tid] = 0; }  // reuse as fill ctr
    int v = a;
    for (int off = 1; off < 64; off <<= 1) {
        int u = __shfl_up(v, off);
        if (lane >= off) v += u;
    }
    if (wvid < 4 && lane == 63) wsum[wvid] = v;
    __syncthreads();
    if (tid < BNODES) {
        int wpre = 0;
        for (int k = 0; k < wvid; k++) wpre += wsum[k];
        base_l[tid] = v + wpre - a;
    }
    __syncthreads();
    for (int i = tid; i < n; i += 512) {
        uint2 r = s[i];
        int dl = r.x >> SRCBITS;
        int src = (int)(r.x & ((1u << SRCBITS) - 1));
        int pos = cb + base_l[dl] + atomicAdd(&cnt_l[dl], 1);
        cv[pos] = make_int2(src, (int)r.y);
        atomicAdd(&degf[dl], __uint_as_float(r.y));
    }
    __syncthreads();
    int gid = (b << BSHIFT) + tid;
    if (tid < BNODES && gid < N) {
        rowptr[gid] = cb + base_l[tid];
        float r = rsqrtf(degf[tid]);
        dis[gid] = r;
        p[gid] = r * x[gid];
    }
}

// Pre-transpose weights to bf16 chunk layout Bt[(k>>3)*NCOLS*8 + n*8 + (k&7)].
__global__ void k_prepB(const float* __restrict__ W2, const float* __restrict__ Wl1,
                        ushort* __restrict__ Bt1, ushort* __restrict__ Bt2) {
    int o = blockIdx.x * blockDim.x + threadIdx.x;
    if (o >= 32768) return;
    {   // Bt1: K=128, NCOLS=256
        int k0 = o & 7, n = (o >> 3) & 255, k8 = o >> 11;
        Bt1[o] = f2bf(W2[(size_t)(k8 * 8 + k0) * 256 + n]);
    }
    {   // Bt2: K=256, NCOLS=128
        int k0 = o & 7, n = (o >> 3) & 127, k8 = o >> 10;
        Bt2[o] = f2bf(Wl1[(size_t)(k8 * 8 + k0) * 128 + n]);
    }
}

// Quarter-wave per node: q = sum(val*p[col]); t = dis*(q+p); tp = (t, dis).
__global__ __launch_bounds__(256) void k_q(const int* __restrict__ rowptr,
                                           const int2* __restrict__ cv,
                                           const float* __restrict__ dis,
                                           const float* __restrict__ p,
                                           float2* __restrict__ tp, int N) {
    int gid = blockIdx.x * blockDim.x + threadIdx.x;
    int wid = gid >> 4;
    int sl = threadIdx.x & 15;
    if (wid >= N) return;
    int beg = rowptr[wid], end = rowptr[wid + 1];
    float s = 0.0f;
    for (int i = beg + sl; i < end; i += 16) {
        int2 pr = cv[i];
        s += __int_as_float(pr.y) * p[pr.x];
    }
    s += __shfl_xor(s, 1);
    s += __shfl_xor(s, 2);
    s += __shfl_xor(s, 4);
    s += __shfl_xor(s, 8);
    if (sl == 0) {
        float r = dis[wid];
        tp[wid] = make_float2(r * (s + p[wid]), r);
    }
}

// Wave per node, rank-1 reconstruction. Per 64-edge batch: stage (wd,t) to
// wave-private LDS, then broadcast-read via ds_read_b128, 4 edges/iter on two
// accumulator pairs. Padding slots (0,0) contribute exactly 0.
__global__ __launch_bounds__(256) void k_agg(const int* __restrict__ rowptr,
                                             const int2* __restrict__ cv,
                                             const float2* __restrict__ tp,
                                             const float* __restrict__ W1,
                                             const float* __restrict__ b1,
                                             uint* __restrict__ z, int N) {
    __shared__ float4 eb[4][32];       // 2 KB: per-wave (wd,t) x64 edge slots
    int tid = threadIdx.x;
    int wvid = tid >> 6, lane = tid & 63;
    int wid = (blockIdx.x * blockDim.x + tid) >> 6;
    if (wid >= N) return;
    float2 w1 = *(const float2*)(W1 + lane * 2);
    float2 bb = *(const float2*)(b1 + lane * 2);
    int beg = rowptr[wid], end = rowptr[wid + 1];
    float ax0 = 0.0f, ay0 = 0.0f, ax1 = 0.0f, ay1 = 0.0f;
    for (int base = beg; base < end; base += 64) {
        int eidx = base + lane;
        float wd = 0.0f, tt = 0.0f;
        if (eidx < end) {
            int2 pr = cv[eidx];
            float2 tps = tp[pr.x];     // 8B gather, L2-resident (800 KB array)
            wd = __int_as_float(pr.y) * tps.y;   // w_e * dis_src
            tt = tps.x;                          // t_src
        }
        ((float2*)&eb[wvid][0])[lane] = make_float2(wd, tt);
        int m = min(64, end - base);
        const float4* ebp = &eb[wvid][0];
        int halves = (m + 1) >> 1;
        int u = 0;
        for (; u + 2 <= halves; u += 2) {
            float4 e2 = ebp[u];
            float4 e3 = ebp[u + 1];
            ax0 = fmaf(e2.x, fmaxf(fmaf(e2.y, w1.x, bb.x), 0.0f), ax0);
            ay0 = fmaf(e2.x, fmaxf(fmaf(e2.y, w1.y, bb.y), 0.0f), ay0);
            ax1 = fmaf(e2.z, fmaxf(fmaf(e2.w, w1.x, bb.x), 0.0f), ax1);
            ay1 = fmaf(e2.z, fmaxf(fmaf(e2.w, w1.y, bb.y), 0.0f), ay1);
            ax0 = fmaf(e3.x, fmaxf(fmaf(e3.y, w1.x, bb.x), 0.0f), ax0);
            ay0 = fmaf(e3.x, fmaxf(fmaf(e3.y, w1.y, bb.y), 0.0f), ay0);
            ax1 = fmaf(e3.z, fmaxf(fmaf(e3.w, w1.x, bb.x), 0.0f), ax1);
            ay1 = fmaf(e3.z, fmaxf(fmaf(e3.w, w1.y, bb.y), 0.0f), ay1);
        }
        if (u < halves) {
            float4 e2 = ebp[u];
            ax0 = fmaf(e2.x, fmaxf(fmaf(e2.y, w1.x, bb.x), 0.0f), ax0);
            ay0 = fmaf(e2.x, fmaxf(fmaf(e2.y, w1.y, bb.y), 0.0f), ay0);
            ax1 = fmaf(e2.z, fmaxf(fmaf(e2.w, w1.x, bb.x), 0.0f), ax1);
            ay1 = fmaf(e2.z, fmaxf(fmaf(e2.w, w1.y, bb.y), 0.0f), ay1);
        }
    }
    float ax = ax0 + ax1, ay = ay0 + ay1;
    float2 tpd = tp[wid];
    float rd = tpd.y;
    float s0 = rd * fmaxf(fmaf(tpd.x, w1.x, bb.x), 0.0f);   // g1[d] self term
    float s1 = rd * fmaxf(fmaf(tpd.x, w1.y, bb.y), 0.0f);
    z[(size_t)wid * 64 + lane] = packbf(rd * (ax + s0), rd * (ay + s1));
}

// Fused MLP: out[i] = relu(relu(z[i]@W2+b2)@Wl1+bl1) . wl2 + bl2.
// 4 waves/block, 32 rows each. Per c-chunk the block cooperatively stages the
// 16KB weight slice into LDS (sB1/sB2) so B-traffic is read once per block,
// not once per wave. st (C->A transform) stays wave-private.
__global__ __launch_bounds__(256) void k_mlp(const ushort* __restrict__ A,    // z bf16 [N][128]
                                             const ushort* __restrict__ Bt1,  // [16][256][8]
                                             const ushort* __restrict__ Bt2,  // [32][128][8]
                                             const float* __restrict__ b2,
                                             const float* __restrict__ bl1,
                                             const float* __restrict__ wl2,
                                             const float* __restrict__ bl2,
                                             float* __restrict__ out, int M) {
    __shared__ ushort sB1[4096];       // 8 KB: Bt1 c-slice (16 rows x 32 cols x 8)
    __shared__ ushort sB2[4096];       // 8 KB: Bt2 c-slice (4 rows x 128 cols x 8)
    __shared__ ushort st[4][32][40];   // 10 KB: per-wave C->A staging
    int tid = threadIdx.x;
    int wv = tid >> 6, lane = tid & 63;
    int l15 = lane & 15, quad = lane >> 4;
    int row0 = blockIdx.x * 128 + wv * 32;
    int r0 = row0 + l15;      r0 = r0 < M ? r0 : M - 1;   // clamp; stores guarded
    int r1 = row0 + 16 + l15; r1 = r1 < M ? r1 : M - 1;

    bf8_t a1[2][4];                       // all A1 frags resident (32 VGPR)
    for (int kc = 0; kc < 4; kc++) {
        a1[0][kc] = *(const bf8_t*)(A + (size_t)r0 * 128 + kc * 32 + quad * 8);
        a1[1][kc] = *(const bf8_t*)(A + (size_t)r1 * 128 + kc * 32 + quad * 8);
    }
    f32x4 acc2[2][8];
    for (int i = 0; i < 2; i++)
        for (int j = 0; j < 8; j++) acc2[i][j] = (f32x4){0.f, 0.f, 0.f, 0.f};

    for (int c = 0; c < 8; c++) {         // 32-col chunk of h2 == 32-k of GEMM2
        // cooperative staging: Bt1 slice = 16 runs of 512B; Bt2 slice = 8KB run
        {
            uint4* s1 = (uint4*)sB1;
            for (int i = tid; i < 512; i += 256) {
                int r = i >> 5, j = i & 31;
                s1[i] = ((const uint4*)(Bt1 + ((size_t)(r * 256 + c * 32)) * 8))[j];
            }
            uint4* s2 = (uint4*)sB2;
            const uint4* g2 = (const uint4*)(Bt2 + (size_t)c * 4096);
            for (int i = tid; i < 512; i += 256) s2[i] = g2[i];
        }
        __syncthreads();
        f32x4 acc1[2][2];
        for (int i = 0; i < 2; i++)
            for (int j = 0; j < 2; j++) acc1[i][j] = (f32x4){0.f, 0.f, 0.f, 0.f};
        for (int kc = 0; kc < 4; kc++)
            for (int nt = 0; nt < 2; nt++) {
                bf8_t b = *(const bf8_t*)(sB1 +
                    ((size_t)((kc * 4 + quad) * 32 + nt * 16 + l15)) * 8);
                acc1[0][nt] = __builtin_amdgcn_mfma_f32_16x16x32_bf16(a1[0][kc], b, acc1[0][nt], 0, 0, 0);
                acc1[1][nt] = __builtin_amdgcn_mfma_f32_16x16x32_bf16(a1[1][kc], b, acc1[1][nt], 0, 0, 0);
            }
        for (int nt = 0; nt < 2; nt++) {
            float bbv = b2[c * 32 + nt * 16 + l15];
            for (int mt = 0; mt < 2; mt++)
                for (int rg = 0; rg < 4; rg++)
                    st[wv][mt * 16 + quad * 4 + rg][nt * 16 + l15] =
                        f2bf(fmaxf(acc1[mt][nt][rg] + bbv, 0.f));
        }
        bf8_t a2_0 = *(const bf8_t*)&st[wv][l15][quad * 8];
        bf8_t a2_1 = *(const bf8_t*)&st[wv][16 + l15][quad * 8];
        for (int nt2 = 0; nt2 < 8; nt2++) {
            bf8_t b = *(const bf8_t*)(sB2 +
                ((size_t)(quad * 128 + nt2 * 16 + l15)) * 8);
            acc2[0][nt2] = __builtin_amdgcn_mfma_f32_16x16x32_bf16(a2_0, b, acc2[0][nt2], 0, 0, 0);
            acc2[1][nt2] = __builtin_amdgcn_mfma_f32_16x16x32_bf16(a2_1, b, acc2[1][nt2], 0, 0, 0);
        }
        __syncthreads();   // all waves done with sB1/sB2 before restage
    }
    float rs[2][4] = {};
    for (int nt2 = 0; nt2 < 8; nt2++) {
        int col = nt2 * 16 + l15;
        float bbv = bl1[col], ww = wl2[col];
        for (int mt = 0; mt < 2; mt++)
            for (int rg = 0; rg < 4; rg++)
                rs[mt][rg] += fmaxf(acc2[mt][nt2][rg] + bbv, 0.f) * ww;
    }
    float base = bl2[0];
    for (int mt = 0; mt < 2; mt++)
        for (int rg = 0; rg < 4; rg++) {
            float s = rs[mt][rg];
            s += __shfl_xor(s, 1);
            s += __shfl_xor(s, 2);
            s += __shfl_xor(s, 4);
            s += __shfl_xor(s, 8);
            int row = row0 + mt * 16 + quad * 4 + rg;
            if (l15 == 0 && row < M) out[row] = s + base;
        }
}

extern "C" void kernel_launch(void* const* d_in, const int* in_sizes, int n_in,
                              void* d_out, int out_size, void* d_ws, size_t ws_size,
                              hipStream_t stream) {
    const float* x   = (const float*)d_in[0];
    const int*   ei  = (const int*)d_in[1];
    const float* ew  = (const float*)d_in[2];
    const float* W1  = (const float*)d_in[3];
    const float* b1  = (const float*)d_in[4];
    const float* W2  = (const float*)d_in[5];
    const float* b2  = (const float*)d_in[6];
    const float* Wl1 = (const float*)d_in[7];
    const float* bl1 = (const float*)d_in[8];
    const float* Wl2 = (const float*)d_in[9];
    const float* bl2 = (const float*)d_in[10];
    float* out = (float*)d_out;
    const int N = in_sizes[0];
    const int E = in_sizes[2];

    const int nbuck = (N + BNODES - 1) >> BSHIFT;             // 391
    const int cap = ((E / nbuck) * 5) / 4 + 1024;             // +~32 sigma slack

    char* w = (char*)d_ws;
    size_t off = 0;
    auto alloc = [&](size_t bytes) -> void* {
        void* p = w + off;
        off = align256(off + bytes);
        return p;
    };
    uint*   z      = (uint*)alloc((size_t)N * 64 * 4);      // bf16 [N][128]
    float2* tp     = (float2*)alloc((size_t)N * 8);         // (t, dis)
    float*  dis    = (float*)alloc((size_t)N * 4);
    float*  p_     = (float*)alloc((size_t)N * 4);
    int*    rowptr = (int*)alloc((size_t)(N + 1) * 4);
    int2*   cv     = (int2*)alloc((size_t)E * 8);
    uint2*  stg    = (uint2*)alloc((size_t)nbuck * cap * 8);
    int*    bfill  = (int*)alloc(512 * 4);
    int*    cvbase = (int*)alloc(512 * 4);
    ushort* Bt1    = (ushort*)alloc(32768 * 2);
    ushort* Bt2    = (ushort*)alloc(32768 * 2);

    hipMemsetAsync(bfill, 0, 512 * 4, stream);
    k_part<<<(E + 2047) / 2048, 256, 0, stream>>>(ei, ew, bfill, stg, E, nbuck, cap);
    k_bscan<<<1, 512, 0, stream>>>(bfill, cvbase, rowptr, nbuck, N, E);
    k_fine<<<nbuck, 512, 0, stream>>>(stg, bfill, cvbase, x, dis, p_, rowptr, cv, cap, N);
    k_prepB<<<128, 256, 0, stream>>>(W2, Wl1, Bt1, Bt2);
    k_q<<<(N * 16 + 255) / 256, 256, 0, stream>>>(rowptr, cv, dis, p_, tp, N);
    k_agg<<<(N + 3) / 4, 256, 0, stream>>>(rowptr, cv, tp, W1, b1, z, N);
    k_mlp<<<(N + 127) / 128, 256, 0, stream>>>((const ushort*)z, Bt1, Bt2,
                                               b2, bl1, Wl2, bl2, out, N);
}

// Round 12
// 211.607 us; speedup vs baseline: 1.0393x; 1.0393x over previous
//
#include <hip/hip_runtime.h>

// GCN on MI355X — round 12: revert k_mlp LDS staging (r11 regression: L1 was
// already absorbing the B re-reads; barriers added pure overhead) and cut the
// dispatch chain 8 -> 6.
//  - k_init = prepB + bfill zeroing (one kernel, replaces memset + k_prepB).
//  - k_fine computes its own cvbase via masked block-reduce over bfill
//    (replaces k_bscan); last block writes rowptr[N].
//  - k_part (per-wave LDS counters) and k_agg (4-edge unroll) kept from r11.
//  - k_mlp: r10 version (direct global B-frags, zero barriers).

#define HD 128
#define HD2 256
#define BSHIFT 8             // 256 nodes per bucket -> 391 buckets
#define BNODES 256
#define SRCBITS 17           // N=100000 < 2^17

typedef __attribute__((ext_vector_type(8))) short bf8_t;   // 8 x bf16 (4 VGPR)
typedef __attribute__((ext_vector_type(4))) float f32x4;

static inline size_t align256(size_t x) { return (x + 255) & ~(size_t)255; }

__device__ inline ushort f2bf(float f) {            // RNE f32 -> bf16
    uint u = __float_as_uint(f);
    uint r = u + 0x7fffu + ((u >> 16) & 1u);
    return (ushort)(r >> 16);
}
__device__ inline uint packbf(float a, float b) {
    return (uint)f2bf(a) | ((uint)f2bf(b) << 16);
}

// prepB (weights -> bf16 chunk layout) + zero bfill. 128 blocks x 256.
__global__ void k_init(const float* __restrict__ W2, const float* __restrict__ Wl1,
                       ushort* __restrict__ Bt1, ushort* __restrict__ Bt2,
                       int* __restrict__ bfill) {
    int o = blockIdx.x * blockDim.x + threadIdx.x;
    if (o < 512) bfill[o] = 0;
    if (o >= 32768) return;
    {   // Bt1: K=128, NCOLS=256: Bt[(k>>3)*256*8 + n*8 + (k&7)]
        int k0 = o & 7, n = (o >> 3) & 255, k8 = o >> 11;
        Bt1[o] = f2bf(W2[(size_t)(k8 * 8 + k0) * 256 + n]);
    }
    {   // Bt2: K=256, NCOLS=128
        int k0 = o & 7, n = (o >> 3) & 127, k8 = o >> 10;
        Bt2[o] = f2bf(Wl1[(size_t)(k8 * 8 + k0) * 128 + n]);
    }
}

// Phase 1: stream edges once, partition into 391 dst-buckets.
// Per-wave LDS counters (4 copies) cut same-address atomic serialization.
__global__ __launch_bounds__(256) void k_part(const int* __restrict__ ei,
                                              const float* __restrict__ ew,
                                              int* __restrict__ bfill,
                                              uint2* __restrict__ stg,
                                              int E, int nbuck, int cap) {
    __shared__ int lcnt[4][512];
    __shared__ int lbase[4][512];
    int tid = threadIdx.x;
    int wvid = tid >> 6;
    for (int i = tid; i < nbuck; i += 256) {
        lcnt[0][i] = 0; lcnt[1][i] = 0; lcnt[2][i] = 0; lcnt[3][i] = 0;
    }
    __syncthreads();
    bool is64 = (ei[1] == 0) && (ei[3] == 0) && (ei[5] == 0) && (ei[7] == 0);
    int e0 = blockIdx.x * 2048;
    uint pack[8]; uint wb[8]; int bkt[8]; int rank[8];
    for (int u = 0; u < 8; u++) {
        int e = e0 + u * 256 + tid;
        bkt[u] = -1;
        if (e < E) {
            int s, d;
            if (is64) { s = ei[2 * e]; d = ei[2 * (E + e)]; }
            else      { s = ei[e];     d = ei[E + e]; }
            bkt[u] = d >> BSHIFT;
            pack[u] = ((uint)(d & (BNODES - 1)) << SRCBITS) | (uint)s;
            wb[u] = __float_as_uint(ew[e]);
            rank[u] = atomicAdd(&lcnt[wvid][bkt[u]], 1);
        }
    }
    __syncthreads();
    for (int i = tid; i < nbuck; i += 256) {
        int t0 = lcnt[0][i], t1 = lcnt[1][i], t2 = lcnt[2][i], t3 = lcnt[3][i];
        int tot = t0 + t1 + t2 + t3;
        int base = tot ? atomicAdd(&bfill[i], tot) : 0;
        lbase[0][i] = base;
        lbase[1][i] = base + t0;
        lbase[2][i] = base + t0 + t1;
        lbase[3][i] = base + t0 + t1 + t2;
    }
    __syncthreads();
    for (int u = 0; u < 8; u++)
        if (bkt[u] >= 0)
            stg[(size_t)bkt[u] * cap + lbase[wvid][bkt[u]] + rank[u]] =
                make_uint2(pack[u], wb[u]);
}

// Phase 2: one 512-thread block per 256-node bucket. Inline cvbase reduction
// (masked block-reduce over bfill) -> LDS count -> scan -> ranked scatter into
// the bucket's private ~32KB cv window. Fused: rowptr emission + deg/dis/p.
__global__ __launch_bounds__(512) void k_fine(const uint2* __restrict__ stg,
                                              const int* __restrict__ bfill,
                                              const float* __restrict__ x,
                                              float* __restrict__ dis,
                                              float* __restrict__ p,
                                              int* __restrict__ rowptr,
                                              int2* __restrict__ cv,
                                              int cap, int N, int E, int nbuck) {
    __shared__ int cnt_l[BNODES];
    __shared__ int base_l[BNODES];
    __shared__ float degf[BNODES];
    __shared__ int wsum[8];
    int b = blockIdx.x, tid = threadIdx.x;
    int lane = tid & 63, wvid = tid >> 6;
    // cvbase[b] = sum_{i<b} bfill[i] via masked block reduction
    int a = (tid < b && tid < nbuck) ? bfill[tid] : 0;   // nbuck <= 512
    for (int off = 32; off > 0; off >>= 1) a += __shfl_xor(a, off);
    if (lane == 0) wsum[wvid] = a;
    __syncthreads();
    int cb = wsum[0] + wsum[1] + wsum[2] + wsum[3] +
             wsum[4] + wsum[5] + wsum[6] + wsum[7];
    int n = bfill[b];
    if (b == nbuck - 1 && tid == 0) rowptr[N] = E;
    const uint2* s = stg + (size_t)b * cap;
    if (tid < BNODES) { cnt_l[tid] = 0; degf[tid] = 1.0f; }
    __syncthreads();
    for (int i = tid; i < n; i += 512)
        atomicAdd(&cnt_l[s[i].x >> SRCBITS], 1);
    __syncthreads();
    int c = 0;
    if (tid < BNODES) { c = cnt_l[tid]; cnt_l[tid] = 0; }  // reuse as fill ctr
    int v = c;
    for (int off = 1; off < 64; off <<= 1) {
        int u = __shfl_up(v, off);
        if (lane >= off) v += u;
    }
    if (wvid < 4 && lane == 63) wsum[wvid] = v;
    __syncthreads();
    if (tid < BNODES) {
        int wpre = 0;
        for (int k = 0; k < wvid; k++) wpre += wsum[k];
        base_l[tid] = v + wpre - c;
    }
    __syncthreads();
    for (int i = tid; i < n; i += 512) {
        uint2 r = s[i];
        int dl = r.x >> SRCBITS;
        int src = (int)(r.x & ((1u << SRCBITS) - 1));
        int pos = cb + base_l[dl] + atomicAdd(&cnt_l[dl], 1);
        cv[pos] = make_int2(src, (int)r.y);
        atomicAdd(&degf[dl], __uint_as_float(r.y));
    }
    __syncthreads();
    int gid = (b << BSHIFT) + tid;
    if (tid < BNODES && gid < N) {
        rowptr[gid] = cb + base_l[tid];
        float r = rsqrtf(degf[tid]);
        dis[gid] = r;
        p[gid] = r * x[gid];
    }
}

// Quarter-wave per node: q = sum(val*p[col]); t = dis*(q+p); tp = (t, dis).
__global__ __launch_bounds__(256) void k_q(const int* __restrict__ rowptr,
                                           const int2* __restrict__ cv,
                                           const float* __restrict__ dis,
                                           const float* __restrict__ p,
                                           float2* __restrict__ tp, int N) {
    int gid = blockIdx.x * blockDim.x + threadIdx.x;
    int wid = gid >> 4;
    int sl = threadIdx.x & 15;
    if (wid >= N) return;
    int beg = rowptr[wid], end = rowptr[wid + 1];
    float s = 0.0f;
    for (int i = beg + sl; i < end; i += 16) {
        int2 pr = cv[i];
        s += __int_as_float(pr.y) * p[pr.x];
    }
    s += __shfl_xor(s, 1);
    s += __shfl_xor(s, 2);
    s += __shfl_xor(s, 4);
    s += __shfl_xor(s, 8);
    if (sl == 0) {
        float r = dis[wid];
        tp[wid] = make_float2(r * (s + p[wid]), r);
    }
}

// Wave per node, rank-1 reconstruction. Per 64-edge batch: stage (wd,t) to
// wave-private LDS, then broadcast-read via ds_read_b128, 4 edges/iter on two
// accumulator pairs. Padding slots (0,0) contribute exactly 0.
__global__ __launch_bounds__(256) void k_agg(const int* __restrict__ rowptr,
                                             const int2* __restrict__ cv,
                                             const float2* __restrict__ tp,
                                             const float* __restrict__ W1,
                                             const float* __restrict__ b1,
                                             uint* __restrict__ z, int N) {
    __shared__ float4 eb[4][32];       // 2 KB: per-wave (wd,t) x64 edge slots
    int tid = threadIdx.x;
    int wvid = tid >> 6, lane = tid & 63;
    int wid = (blockIdx.x * blockDim.x + tid) >> 6;
    if (wid >= N) return;
    float2 w1 = *(const float2*)(W1 + lane * 2);
    float2 bb = *(const float2*)(b1 + lane * 2);
    int beg = rowptr[wid], end = rowptr[wid + 1];
    float ax0 = 0.0f, ay0 = 0.0f, ax1 = 0.0f, ay1 = 0.0f;
    for (int base = beg; base < end; base += 64) {
        int eidx = base + lane;
        float wd = 0.0f, tt = 0.0f;
        if (eidx < end) {
            int2 pr = cv[eidx];
            float2 tps = tp[pr.x];     // 8B gather, L2-resident (800 KB array)
            wd = __int_as_float(pr.y) * tps.y;   // w_e * dis_src
            tt = tps.x;                          // t_src
        }
        ((float2*)&eb[wvid][0])[lane] = make_float2(wd, tt);
        int m = min(64, end - base);
        const float4* ebp = &eb[wvid][0];
        int halves = (m + 1) >> 1;
        int u = 0;
        for (; u + 2 <= halves; u += 2) {
            float4 e2 = ebp[u];
            float4 e3 = ebp[u + 1];
            ax0 = fmaf(e2.x, fmaxf(fmaf(e2.y, w1.x, bb.x), 0.0f), ax0);
            ay0 = fmaf(e2.x, fmaxf(fmaf(e2.y, w1.y, bb.y), 0.0f), ay0);
            ax1 = fmaf(e2.z, fmaxf(fmaf(e2.w, w1.x, bb.x), 0.0f), ax1);
            ay1 = fmaf(e2.z, fmaxf(fmaf(e2.w, w1.y, bb.y), 0.0f), ay1);
            ax0 = fmaf(e3.x, fmaxf(fmaf(e3.y, w1.x, bb.x), 0.0f), ax0);
            ay0 = fmaf(e3.x, fmaxf(fmaf(e3.y, w1.y, bb.y), 0.0f), ay0);
            ax1 = fmaf(e3.z, fmaxf(fmaf(e3.w, w1.x, bb.x), 0.0f), ax1);
            ay1 = fmaf(e3.z, fmaxf(fmaf(e3.w, w1.y, bb.y), 0.0f), ay1);
        }
        if (u < halves) {
            float4 e2 = ebp[u];
            ax0 = fmaf(e2.x, fmaxf(fmaf(e2.y, w1.x, bb.x), 0.0f), ax0);
            ay0 = fmaf(e2.x, fmaxf(fmaf(e2.y, w1.y, bb.y), 0.0f), ay0);
            ax1 = fmaf(e2.z, fmaxf(fmaf(e2.w, w1.x, bb.x), 0.0f), ax1);
            ay1 = fmaf(e2.z, fmaxf(fmaf(e2.w, w1.y, bb.y), 0.0f), ay1);
        }
    }
    float ax = ax0 + ax1, ay = ay0 + ay1;
    float2 tpd = tp[wid];
    float rd = tpd.y;
    float s0 = rd * fmaxf(fmaf(tpd.x, w1.x, bb.x), 0.0f);   // g1[d] self term
    float s1 = rd * fmaxf(fmaf(tpd.x, w1.y, bb.y), 0.0f);
    z[(size_t)wid * 64 + lane] = packbf(rd * (ax + s0), rd * (ay + s1));
}

// Fused MLP (r10 version): out[i] = relu(relu(z[i]@W2+b2)@Wl1+bl1).wl2 + bl2.
// 4 independent waves/block, 32 rows each; B-frags direct from global (L1-hot).
__global__ __launch_bounds__(256) void k_mlp(const ushort* __restrict__ A,    // z bf16 [N][128]
                                             const ushort* __restrict__ Bt1,  // [16][256][8]
                                             const ushort* __restrict__ Bt2,  // [32][128][8]
                                             const float* __restrict__ b2,
                                             const float* __restrict__ bl1,
                                             const float* __restrict__ wl2,
                                             const float* __restrict__ bl2,
                                             float* __restrict__ out, int M) {
    __shared__ ushort st[4][32][40];   // per-wave C->A staging; 80B row stride
    int tid = threadIdx.x;
    int wv = tid >> 6, lane = tid & 63;
    int l15 = lane & 15, quad = lane >> 4;
    int row0 = blockIdx.x * 128 + wv * 32;
    int r0 = row0 + l15;      r0 = r0 < M ? r0 : M - 1;   // clamp; stores guarded
    int r1 = row0 + 16 + l15; r1 = r1 < M ? r1 : M - 1;

    bf8_t a1[2][4];                       // all A1 frags resident (32 VGPR)
    for (int kc = 0; kc < 4; kc++) {
        a1[0][kc] = *(const bf8_t*)(A + (size_t)r0 * 128 + kc * 32 + quad * 8);
        a1[1][kc] = *(const bf8_t*)(A + (size_t)r1 * 128 + kc * 32 + quad * 8);
    }
    f32x4 acc2[2][8];
    for (int i = 0; i < 2; i++)
        for (int j = 0; j < 8; j++) acc2[i][j] = (f32x4){0.f, 0.f, 0.f, 0.f};

    for (int c = 0; c < 8; c++) {         // 32-col chunk of h2 == 32-k of GEMM2
        f32x4 acc1[2][2];
        for (int i = 0; i < 2; i++)
            for (int j = 0; j < 2; j++) acc1[i][j] = (f32x4){0.f, 0.f, 0.f, 0.f};
        for (int kc = 0; kc < 4; kc++)
            for (int nt = 0; nt < 2; nt++) {
                bf8_t b = *(const bf8_t*)(Bt1 +
                    ((size_t)(kc * 4 + quad) * 256 + c * 32 + nt * 16 + l15) * 8);
                acc1[0][nt] = __builtin_amdgcn_mfma_f32_16x16x32_bf16(a1[0][kc], b, acc1[0][nt], 0, 0, 0);
                acc1[1][nt] = __builtin_amdgcn_mfma_f32_16x16x32_bf16(a1[1][kc], b, acc1[1][nt], 0, 0, 0);
            }
        for (int nt = 0; nt < 2; nt++) {
            float bb = b2[c * 32 + nt * 16 + l15];
            for (int mt = 0; mt < 2; mt++)
                for (int rg = 0; rg < 4; rg++)
                    st[wv][mt * 16 + quad * 4 + rg][nt * 16 + l15] =
                        f2bf(fmaxf(acc1[mt][nt][rg] + bb, 0.f));
        }
        bf8_t a2_0 = *(const bf8_t*)&st[wv][l15][quad * 8];
        bf8_t a2_1 = *(const bf8_t*)&st[wv][16 + l15][quad * 8];
        for (int nt2 = 0; nt2 < 8; nt2++) {
            bf8_t b = *(const bf8_t*)(Bt2 +
                ((size_t)(c * 4 + quad) * 128 + nt2 * 16 + l15) * 8);
            acc2[0][nt2] = __builtin_amdgcn_mfma_f32_16x16x32_bf16(a2_0, b, acc2[0][nt2], 0, 0, 0);
            acc2[1][nt2] = __builtin_amdgcn_mfma_f32_16x16x32_bf16(a2_1, b, acc2[1][nt2], 0, 0, 0);
        }
    }
    float rs[2][4] = {};
    for (int nt2 = 0; nt2 < 8; nt2++) {
        int col = nt2 * 16 + l15;
        float bb = bl1[col], ww = wl2[col];
        for (int mt = 0; mt < 2; mt++)
            for (int rg = 0; rg < 4; rg++)
                rs[mt][rg] += fmaxf(acc2[mt][nt2][rg] + bb, 0.f) * ww;
    }
    float base = bl2[0];
    for (int mt = 0; mt < 2; mt++)
        for (int rg = 0; rg < 4; rg++) {
            float s = rs[mt][rg];
            s += __shfl_xor(s, 1);
            s += __shfl_xor(s, 2);
            s += __shfl_xor(s, 4);
            s += __shfl_xor(s, 8);
            int row = row0 + mt * 16 + quad * 4 + rg;
            if (l15 == 0 && row < M) out[row] = s + base;
        }
}

extern "C" void kernel_launch(void* const* d_in, const int* in_sizes, int n_in,
                              void* d_out, int out_size, void* d_ws, size_t ws_size,
                              hipStream_t stream) {
    const float* x   = (const float*)d_in[0];
    const int*   ei  = (const int*)d_in[1];
    const float* ew  = (const float*)d_in[2];
    const float* W1  = (const float*)d_in[3];
    const float* b1  = (const float*)d_in[4];
    const float* W2  = (const float*)d_in[5];
    const float* b2  = (const float*)d_in[6];
    const float* Wl1 = (const float*)d_in[7];
    const float* bl1 = (const float*)d_in[8];
    const float* Wl2 = (const float*)d_in[9];
    const float* bl2 = (const float*)d_in[10];
    float* out = (float*)d_out;
    const int N = in_sizes[0];
    const int E = in_sizes[2];

    const int nbuck = (N + BNODES - 1) >> BSHIFT;             // 391
    const int cap = ((E / nbuck) * 5) / 4 + 1024;             // +~32 sigma slack

    char* w = (char*)d_ws;
    size_t off = 0;
    auto alloc = [&](size_t bytes) -> void* {
        void* p = w + off;
        off = align256(off + bytes);
        return p;
    };
    uint*   z      = (uint*)alloc((size_t)N * 64 * 4);      // bf16 [N][128]
    float2* tp     = (float2*)alloc((size_t)N * 8);         // (t, dis)
    float*  dis    = (float*)alloc((size_t)N * 4);
    float*  p_     = (float*)alloc((size_t)N * 4);
    int*    rowptr = (int*)alloc((size_t)(N + 1) * 4);
    int2*   cv     = (int2*)alloc((size_t)E * 8);
    uint2*  stg    = (uint2*)alloc((size_t)nbuck * cap * 8);
    int*    bfill  = (int*)alloc(512 * 4);
    ushort* Bt1    = (ushort*)alloc(32768 * 2);
    ushort* Bt2    = (ushort*)alloc(32768 * 2);

    k_init<<<128, 256, 0, stream>>>(W2, Wl1, Bt1, Bt2, bfill);
    k_part<<<(E + 2047) / 2048, 256, 0, stream>>>(ei, ew, bfill, stg, E, nbuck, cap);
    k_fine<<<nbuck, 512, 0, stream>>>(stg, bfill, x, dis, p_, rowptr, cv, cap, N, E, nbuck);
    k_q<<<(N * 16 + 255) / 256, 256, 0, stream>>>(rowptr, cv, dis, p_, tp, N);
    k_agg<<<(N + 3) / 4, 256, 0, stream>>>(rowptr, cv, tp, W1, b1, z, N);
    k_mlp<<<(N + 127) / 128, 256, 0, stream>>>((const ushort*)z, Bt1, Bt2,
                                               b2, bl1, Wl2, bl2, out, N);
}